// Round 11
// baseline (510.829 us; speedup 1.0000x reference)
//
#include <hip/hip_runtime.h>
#include <stdint.h>

// Round 11 = round 10 with bank-dispersed LDS strides.
// r10's 30M bank conflicts: chunk offset cg*16 u32 -> 16cg mod 32 in {0,16} =
// 4-way alias on every KtT/aap/bbp read; col stride 132 -> j2*132*4 mod 32 = 0
// = 8-way alias on transpose b16 writes. Fix: chunk stride 20 u32 (20cg mod 32
// hits all 8 bank quads, 16B-aligned), column stride 164 (mod 32 = 4 spreads
// row lanes and transpose writes). Chunks padded to 16 used u32 (3 zero pads):
// reads are 4x uint4, col dot chain split into 2 accumulators.
// Everything else identical to r10 (640 thr, symmetric Sinkhorn, Kt[3][13]
// registers for row pass, KtT in LDS for col pass, no combine phase).

#define NN 200
#define NMAT 2560
#define NITER 20

// LDS layout (u32)
#define KTT_U32 32800    // 200 cols x 164
#define AAP_OFF 32800    // 160 (8 chunks x 20)
#define BBP_OFF 32960    // 160
#define WRED_OFF 33120   // 16
#define SM_U32 33136     // 132,544 bytes

typedef uint32_t u32;
typedef uint16_t u16;

__device__ __forceinline__ u32 bpack(float lo, float hi){
  u32 a=__float_as_uint(lo); a += 0x7fffu + ((a>>16)&1u);
  u32 b=__float_as_uint(hi); b += 0x7fffu + ((b>>16)&1u);
  return (a>>16) | (b & 0xffff0000u);
}
__device__ __forceinline__ float dot2bf(u32 kp, u32 bp, float acc){
  asm("v_dot2_f32_bf16 %0, %1, %2, %0" : "+v"(acc) : "v"(kp), "v"(bp));
  return acc;
}
template<int CTRL>
__device__ __forceinline__ float dpp_add(float x){
  return x + __int_as_float(__builtin_amdgcn_update_dpp(0, __float_as_int(x), CTRL, 0xF, 0xF, true));
}
template<int PAT>
__device__ __forceinline__ float swz_add(float x){
  return x + __int_as_float(__builtin_amdgcn_ds_swizzle(__float_as_int(x), PAT));
}
__device__ __forceinline__ float xch8(float x){   // value from lane^8
  return __int_as_float(__builtin_amdgcn_update_dpp(0, __float_as_int(x), 0x128, 0xF, 0xF, true));
}
__device__ __forceinline__ float pl16_add(float x){
#if __has_builtin(__builtin_amdgcn_permlane16_swap)
  auto r = __builtin_amdgcn_permlane16_swap(__float_as_uint(x), __float_as_uint(x), false, false);
  return __uint_as_float(r[0]) + __uint_as_float(r[1]);
#else
  return x + __shfl_xor(x, 16, 64);
#endif
}
__device__ __forceinline__ float pl32_add(float x){
#if __has_builtin(__builtin_amdgcn_permlane32_swap)
  auto r = __builtin_amdgcn_permlane32_swap(__float_as_uint(x), __float_as_uint(x), false, false);
  return __uint_as_float(r[0]) + __uint_as_float(r[1]);
#else
  return x + __shfl_xor(x, 32, 64);
#endif
}

// ---------------- prep: piecewise-affine MLP coefficients ------------------
// ws (f32): [0..32) knots (unsorted); [32..) AB[33][200][2] interleaved.
__global__ void __launch_bounds__(256)
prep_kernel(const float* __restrict__ W1, const float* __restrict__ b1,
            const float* __restrict__ W2, const float* __restrict__ b2,
            float* __restrict__ ws) {
  __shared__ float kn[32], sg[32], w1s[32], b1s[32];
  __shared__ int ord[32];
  const int tid = threadIdx.x;
  if (tid < 32) {
    const float w1 = W1[tid], bv = b1[tid];
    float knot, s;
    if (w1 != 0.f) { knot = -bv / w1; s = (w1 > 0.f) ? 1.f : -1.f; }
    else           { knot = (bv > 0.f) ? -1e30f : 1e30f; s = 1.f; }
    kn[tid] = knot; sg[tid] = s; w1s[tid] = w1; b1s[tid] = bv;
    ws[tid] = knot;
  }
  __syncthreads();
  if (tid < 32) {
    int rk = 0;
#pragma unroll
    for (int v = 0; v < 32; ++v) {
      const float kv = kn[v];
      rk += (kv < kn[tid] || (kv == kn[tid] && v < tid)) ? 1 : 0;
    }
    ord[rk] = tid;
  }
  __syncthreads();
  if (tid < NN) {
    float w2l[32];
#pragma unroll
    for (int u = 0; u < 32; ++u) w2l[u] = W2[tid*32 + u];
    float A = 0.f, Bv = b2[tid];
#pragma unroll
    for (int u = 0; u < 32; ++u)
      if (sg[u] < 0.f) { A += w2l[u]*w1s[u]; Bv += w2l[u]*b1s[u]; }
    float* AB = ws + 32;
    AB[(0*NN + tid)*2 + 0] = A;
    AB[(0*NN + tid)*2 + 1] = Bv;
    for (int s = 0; s < 32; ++s) {
      const int u = ord[s];
      A  += sg[u]*w2l[u]*w1s[u];
      Bv += sg[u]*w2l[u]*b1s[u];
      AB[((s+1)*NN + tid)*2 + 0] = A;
      AB[((s+1)*NN + tid)*2 + 1] = Bv;
    }
  }
}

// ---------------- main ------------------------------------------------------
__global__ void __launch_bounds__(640)
sinkhorn_main(const float* __restrict__ random_,    // [256*200]
              const float* __restrict__ ordered_t,  // [2560*200]
              const float* __restrict__ random_t,   // [2560*200]
              const float* __restrict__ gumbel,     // [2560*200*200]
              const float* __restrict__ ws,
              float* __restrict__ out) {
  extern __shared__ u32 sm[];
  u32* KtT = sm;
  u32* aap = sm + AAP_OFF;
  u32* bbp = sm + BBP_OFF;
  float* wred = (float*)(sm + WRED_OFF);

  const int tid  = threadIdx.x;
  const int m    = blockIdx.x;
  const int bidx = m & 255;

  const int w    = tid >> 6;          // 0..9
  const int lane = tid & 63;
  const int cg   = lane & 7;          // bits 0-2: chunk group
  const int rgl  = (lane >> 3) & 7;   // bits 3-5
  const int rg   = w * 8 + rgl;       // 0..79
  const bool nr3 = (rg < 40);         // wave-uniform
  const int nr   = nr3 ? 3 : 2;       // rows/cols owned: {80d+rg : d<nr}
  const int cbase = 25*cg + (cg & 1); // even; csz 26/24
  const int csz   = 26 - 2*(cg & 1);

  // ---- zero KtT (pads) + init vectors (20-stride chunks, pads zero) -------
  {
    const uint4 z = make_uint4(0u,0u,0u,0u);
    for (int i = tid; i < KTT_U32/4; i += 640)
      *(uint4*)(KtT + i*4) = z;
    if (tid < 160) {
      const int cgc = tid / 20, sl = tid - 20*cgc;
      bbp[tid] = (sl < 13 - (cgc & 1)) ? 0x3f803f80u : 0u;  // {1.0bf,1.0bf}
      aap[tid] = 0u;
    }
  }

  // ---- per-thread pair slots: j = 40d + rg/2 -> chunk cgb, 20-stride ------
  int s0, s1, s2;
  {
    const int jb = rg >> 1;
#pragma unroll
    for (int d = 0; d < 3; ++d) {
      const int j = 40*d + jb;
      const int cgb = (j>=13)+(j>=25)+(j>=38)+(j>=50)+(j>=63)+(j>=75)+(j>=88);
      const int sl = cgb*20 + j - ((25*cgb + (cgb&1)) >> 1);
      if (d == 0) s0 = sl; else if (d == 1) s1 = sl; else s2 = sl;
    }
  }

  // ---- build Kt[3][13] from gumbel (register staging) + MLP affine --------
  float xr[3] = {0.f, 0.f, 0.f}; int ii[3] = {0, 0, 0};
#pragma unroll
  for (int d = 0; d < 3; ++d)
    if (d < nr) xr[d] = random_[bidx*NN + 80*d + rg];
  for (int u = 0; u < 32; ++u) {
    const float kn = ws[u];
#pragma unroll
    for (int d = 0; d < 3; ++d) ii[d] += (kn < xr[d]) ? 1 : 0;
  }
  const float* ABt = ws + 32;
  const float* gmat = gumbel + (size_t)m * (NN*NN);

  u32 Kt[3][13];
#pragma unroll
  for (int d = 0; d < 3; ++d) {
    if (d < nr) {
      const float* grow = gmat + (size_t)(80*d + rg)*NN + cbase;
      float2 g[13];
#pragma unroll
      for (int k = 0; k < 13; ++k)
        g[k] = (2*k < csz) ? *(const float2*)(grow + 2*k) : make_float2(0.f, 0.f);
      const float x = xr[d];
      const float* ab = ABt + (size_t)(ii[d]*NN + cbase) * 2;
#pragma unroll
      for (int k = 0; k < 13; ++k) {
        u32 pk = 0;
        if (2*k < csz) {
          const float4 A = *(const float4*)(ab + 4*k);   // {A0,B0,A1,B1}
          pk = bpack(__expf(fmaf(x, A.x, A.y) + g[k].x),
                     __expf(fmaf(x, A.z, A.w) + g[k].y));
        }
        Kt[d][k] = pk;
      }
    } else {
#pragma unroll
      for (int k = 0; k < 13; ++k) Kt[d][k] = 0;
    }
  }
  __syncthreads();   // zero-fill complete before transpose writes

  // ---- transpose into KtT: u16 idx = 2*(col*164 + chunk-slot) + (rg&1) ----
#pragma unroll
  for (int d = 0; d < 3; ++d) {
    if (d < nr) {
      const int sd = (d == 0) ? s0 : (d == 1) ? s1 : s2;
      u16* tb = (u16*)KtT;
      const int h = (rg & 1);
#pragma unroll
      for (int k = 0; k < 13; ++k) {
        if (2*k < csz) {
          tb[((cbase + 2*k    )*164 + sd)*2 + h] = (u16)(Kt[d][k] & 0xffffu);
          tb[((cbase + 2*k + 1)*164 + sd)*2 + h] = (u16)(Kt[d][k] >> 16);
        }
      }
    }
  }
  __syncthreads();

  // ---- 20 symmetric Sinkhorn iterations ------------------------------------
  const u32* bbv = bbp + cg*20;
  const u32* aav = aap + cg*20;
  float a0, a1, a2 = 0.f, b0 = 1.f, b1 = 1.f, b2 = 1.f;

  for (int it = 0; it < NITER; ++it) {
    // row pass: a_r = 1/sum_c K[r][c] b_c  (K from registers)
    u32 bv[16];
    *(uint4*)&bv[0]  = *(const uint4*)(bbv);
    *(uint4*)&bv[4]  = *(const uint4*)(bbv + 4);
    *(uint4*)&bv[8]  = *(const uint4*)(bbv + 8);
    *(uint4*)&bv[12] = *(const uint4*)(bbv + 12);
    float c0 = 0.f, c1 = 0.f, c2 = 0.f;
#pragma unroll
    for (int k = 0; k < 13; ++k) {
      c0 = dot2bf(Kt[0][k], bv[k], c0);
      c1 = dot2bf(Kt[1][k], bv[k], c1);
      c2 = dot2bf(Kt[2][k], bv[k], c2);
    }
    c0 = swz_add<0x101F>(dpp_add<0x4E>(dpp_add<0xB1>(c0)));
    c1 = swz_add<0x101F>(dpp_add<0x4E>(dpp_add<0xB1>(c1)));
    c2 = swz_add<0x101F>(dpp_add<0x4E>(dpp_add<0xB1>(c2)));
    a0 = __builtin_amdgcn_rcpf(c0);
    a1 = __builtin_amdgcn_rcpf(c1);
    a2 = nr3 ? __builtin_amdgcn_rcpf(c2) : 0.f;
    {
      const float a0s = xch8(a0), a1s = xch8(a1), a2s = xch8(a2);
      if (cg == 0 && !(rg & 1)) {
        aap[s0] = bpack(a0, a0s);
        aap[s1] = bpack(a1, a1s);
        if (nr3) aap[s2] = bpack(a2, a2s);
      }
    }
    __syncthreads();

    // col pass: b_c = 1/sum_r K[r][c] a_r  (K^T from LDS, same shape)
    u32 av[16];
    *(uint4*)&av[0]  = *(const uint4*)(aav);
    *(uint4*)&av[4]  = *(const uint4*)(aav + 4);
    *(uint4*)&av[8]  = *(const uint4*)(aav + 8);
    *(uint4*)&av[12] = *(const uint4*)(aav + 12);
    float e0 = 0.f, e1 = 0.f, e2 = 0.f;
#pragma unroll
    for (int d = 0; d < 3; ++d) {
      if (d < nr) {
        const u32* kc = KtT + (80*d + rg)*164 + cg*20;
        u32 kv[16];
        *(uint4*)&kv[0]  = *(const uint4*)(kc);
        *(uint4*)&kv[4]  = *(const uint4*)(kc + 4);
        *(uint4*)&kv[8]  = *(const uint4*)(kc + 8);
        *(uint4*)&kv[12] = *(const uint4*)(kc + 12);
        float aE = 0.f, aO = 0.f;
#pragma unroll
        for (int k = 0; k < 8; ++k) {
          aE = dot2bf(kv[2*k],     av[2*k],     aE);
          aO = dot2bf(kv[2*k + 1], av[2*k + 1], aO);
        }
        const float acc = aE + aO;
        if (d == 0) e0 = acc; else if (d == 1) e1 = acc; else e2 = acc;
      }
    }
    e0 = swz_add<0x101F>(dpp_add<0x4E>(dpp_add<0xB1>(e0)));
    e1 = swz_add<0x101F>(dpp_add<0x4E>(dpp_add<0xB1>(e1)));
    e2 = swz_add<0x101F>(dpp_add<0x4E>(dpp_add<0xB1>(e2)));
    b0 = __builtin_amdgcn_rcpf(e0);
    b1 = __builtin_amdgcn_rcpf(e1);
    b2 = nr3 ? __builtin_amdgcn_rcpf(e2) : 0.f;
    {
      const float b0s = xch8(b0), b1s = xch8(b1), b2s = xch8(b2);
      if (cg == 0 && !(rg & 1)) {
        bbp[s0] = bpack(b0, b0s);
        bbp[s1] = bpack(b1, b1s);
        if (nr3) bbp[s2] = bpack(b2, b2s);
      }
    }
    __syncthreads();
  }

  // ---- loss: rec_c = b_c * sum_r K[r][c] (a_r * r_r) ------------------------
  {
    const float r0 = a0 * random_t[m*NN + rg];
    const float r1 = a1 * random_t[m*NN + 80 + rg];
    const float r2 = nr3 ? a2 * random_t[m*NN + 160 + rg] : 0.f;
    const float r0s = xch8(r0), r1s = xch8(r1), r2s = xch8(r2);
    if (cg == 0 && !(rg & 1)) {
      aap[s0] = bpack(r0, r0s);
      aap[s1] = bpack(r1, r1s);
      if (nr3) aap[s2] = bpack(r2, r2s);
    }
  }
  __syncthreads();
  float lacc = 0.f;
  {
    u32 av[16];
    *(uint4*)&av[0]  = *(const uint4*)(aav);
    *(uint4*)&av[4]  = *(const uint4*)(aav + 4);
    *(uint4*)&av[8]  = *(const uint4*)(aav + 8);
    *(uint4*)&av[12] = *(const uint4*)(aav + 12);
    float e0 = 0.f, e1 = 0.f, e2 = 0.f;
#pragma unroll
    for (int d = 0; d < 3; ++d) {
      if (d < nr) {
        const u32* kc = KtT + (80*d + rg)*164 + cg*20;
        u32 kv[16];
        *(uint4*)&kv[0]  = *(const uint4*)(kc);
        *(uint4*)&kv[4]  = *(const uint4*)(kc + 4);
        *(uint4*)&kv[8]  = *(const uint4*)(kc + 8);
        *(uint4*)&kv[12] = *(const uint4*)(kc + 12);
        float aE = 0.f, aO = 0.f;
#pragma unroll
        for (int k = 0; k < 8; ++k) {
          aE = dot2bf(kv[2*k],     av[2*k],     aE);
          aO = dot2bf(kv[2*k + 1], av[2*k + 1], aO);
        }
        const float acc = aE + aO;
        if (d == 0) e0 = acc; else if (d == 1) e1 = acc; else e2 = acc;
      }
    }
    e0 = swz_add<0x101F>(dpp_add<0x4E>(dpp_add<0xB1>(e0)));
    e1 = swz_add<0x101F>(dpp_add<0x4E>(dpp_add<0xB1>(e1)));
    e2 = swz_add<0x101F>(dpp_add<0x4E>(dpp_add<0xB1>(e2)));
    const float o0 = ordered_t[m*NN + rg];
    const float o1 = ordered_t[m*NN + 80 + rg];
    const float d0 = o0 - b0*e0;
    const float d1 = o1 - b1*e1;
    lacc = fmaf(d0, d0, d1*d1);
    if (nr3) {
      const float o2 = ordered_t[m*NN + 160 + rg];
      const float d2 = o2 - b2*e2;
      lacc = fmaf(d2, d2, lacc);
    }
    lacc = (cg == 0) ? lacc : 0.f;    // one count per column
  }
  lacc = dpp_add<0xB1>(lacc);
  lacc = dpp_add<0x4E>(lacc);
  lacc = swz_add<0x101F>(lacc);
  lacc = dpp_add<0x128>(lacc);
  lacc = pl16_add(lacc);
  lacc = pl32_add(lacc);
  if (lane == 0) wred[w] = lacc;
  __syncthreads();
  if (tid == 0) {
    float ssum = 0.f;
#pragma unroll
    for (int i = 0; i < 10; ++i) ssum += wred[i];
    atomicAdd(out, ssum * (1.0f / 512000.0f));
  }
}

extern "C" void kernel_launch(void* const* d_in, const int* in_sizes, int n_in,
                              void* d_out, int out_size, void* d_ws, size_t ws_size,
                              hipStream_t stream) {
  (void)in_sizes; (void)n_in; (void)ws_size; (void)out_size;
  const float* random_  = (const float*)d_in[0];
  const float* ordered  = (const float*)d_in[1];
  const float* random_t = (const float*)d_in[2];
  const float* gumbel   = (const float*)d_in[3];
  const float* W1 = (const float*)d_in[4];
  const float* b1 = (const float*)d_in[5];
  const float* W2 = (const float*)d_in[6];
  const float* b2 = (const float*)d_in[7];
  float* out = (float*)d_out;
  float* ws  = (float*)d_ws;   // needs 52,928 B

  const size_t smem = SM_U32 * sizeof(u32);  // 132,544 B
  hipFuncSetAttribute((const void*)sinkhorn_main,
                      hipFuncAttributeMaxDynamicSharedMemorySize, (int)smem);
  prep_kernel<<<1, 256, 0, stream>>>(W1, b1, W2, b2, ws);
  hipMemsetAsync(out, 0, sizeof(float), stream);
  sinkhorn_main<<<NMAT, 640, smem, stream>>>(random_, ordered, random_t, gumbel, ws, out);
}

// Round 12
// 509.664 us; speedup vs baseline: 1.0023x; 1.0023x over previous
//
#include <hip/hip_runtime.h>
#include <stdint.h>

// Round 12 = round 10 (494us anchor) + bank-dispersed chunk offsets ONLY.
// r10 kv read: addr = row*132 + cg*16 -> start bank (4rgl+16cg) mod 32 in
// {0,16}+4rgl: all even-cg lanes alias -> conflicts on every col-pass read.
// r11's wider-stride+padded-read variant regressed (46M conflicts): more read
// volume, multi-variable. This round: keep r10's EXACT read structure
// (13 u32 = 3x uint4 + 1 dword, single dot accumulator), change only:
//   chunk offset  cg*16      -> coff(cg) = 16cg + 4(cg>>1)  ({0,16,36,...,124},
//                               starts mod 32 all distinct)
//   column stride 132        -> 140  (140*rgl mod 32 = 12rgl, distinct)
// Single-variable experiment: conflicts <10M => layout was the cost;
// still ~30M => counter dominated elsewhere, pivot to persistent blocks.

#define NN 200
#define NMAT 2560
#define NITER 20
#define CSTR 140         // column stride in u32

// LDS layout (u32)
#define KTT_U32 28000    // 200 cols x 140
#define AAP_OFF 28000    // 140
#define BBP_OFF 28140    // 140
#define WRED_OFF 28280   // 16
#define SM_U32 28296     // 113,184 bytes

typedef uint32_t u32;
typedef uint16_t u16;

__device__ __forceinline__ u32 bpack(float lo, float hi){
  u32 a=__float_as_uint(lo); a += 0x7fffu + ((a>>16)&1u);
  u32 b=__float_as_uint(hi); b += 0x7fffu + ((b>>16)&1u);
  return (a>>16) | (b & 0xffff0000u);
}
__device__ __forceinline__ float dot2bf(u32 kp, u32 bp, float acc){
  asm("v_dot2_f32_bf16 %0, %1, %2, %0" : "+v"(acc) : "v"(kp), "v"(bp));
  return acc;
}
template<int CTRL>
__device__ __forceinline__ float dpp_add(float x){
  return x + __int_as_float(__builtin_amdgcn_update_dpp(0, __float_as_int(x), CTRL, 0xF, 0xF, true));
}
template<int PAT>
__device__ __forceinline__ float swz_add(float x){
  return x + __int_as_float(__builtin_amdgcn_ds_swizzle(__float_as_int(x), PAT));
}
__device__ __forceinline__ float xch8(float x){   // value from lane^8
  return __int_as_float(__builtin_amdgcn_update_dpp(0, __float_as_int(x), 0x128, 0xF, 0xF, true));
}
__device__ __forceinline__ float pl16_add(float x){
#if __has_builtin(__builtin_amdgcn_permlane16_swap)
  auto r = __builtin_amdgcn_permlane16_swap(__float_as_uint(x), __float_as_uint(x), false, false);
  return __uint_as_float(r[0]) + __uint_as_float(r[1]);
#else
  return x + __shfl_xor(x, 16, 64);
#endif
}
__device__ __forceinline__ float pl32_add(float x){
#if __has_builtin(__builtin_amdgcn_permlane32_swap)
  auto r = __builtin_amdgcn_permlane32_swap(__float_as_uint(x), __float_as_uint(x), false, false);
  return __uint_as_float(r[0]) + __uint_as_float(r[1]);
#else
  return x + __shfl_xor(x, 32, 64);
#endif
}

// ---------------- prep: piecewise-affine MLP coefficients ------------------
// ws (f32): [0..32) knots (unsorted); [32..) AB[33][200][2] interleaved.
__global__ void __launch_bounds__(256)
prep_kernel(const float* __restrict__ W1, const float* __restrict__ b1,
            const float* __restrict__ W2, const float* __restrict__ b2,
            float* __restrict__ ws) {
  __shared__ float kn[32], sg[32], w1s[32], b1s[32];
  __shared__ int ord[32];
  const int tid = threadIdx.x;
  if (tid < 32) {
    const float w1 = W1[tid], bv = b1[tid];
    float knot, s;
    if (w1 != 0.f) { knot = -bv / w1; s = (w1 > 0.f) ? 1.f : -1.f; }
    else           { knot = (bv > 0.f) ? -1e30f : 1e30f; s = 1.f; }
    kn[tid] = knot; sg[tid] = s; w1s[tid] = w1; b1s[tid] = bv;
    ws[tid] = knot;
  }
  __syncthreads();
  if (tid < 32) {
    int rk = 0;
#pragma unroll
    for (int v = 0; v < 32; ++v) {
      const float kv = kn[v];
      rk += (kv < kn[tid] || (kv == kn[tid] && v < tid)) ? 1 : 0;
    }
    ord[rk] = tid;
  }
  __syncthreads();
  if (tid < NN) {
    float w2l[32];
#pragma unroll
    for (int u = 0; u < 32; ++u) w2l[u] = W2[tid*32 + u];
    float A = 0.f, Bv = b2[tid];
#pragma unroll
    for (int u = 0; u < 32; ++u)
      if (sg[u] < 0.f) { A += w2l[u]*w1s[u]; Bv += w2l[u]*b1s[u]; }
    float* AB = ws + 32;
    AB[(0*NN + tid)*2 + 0] = A;
    AB[(0*NN + tid)*2 + 1] = Bv;
    for (int s = 0; s < 32; ++s) {
      const int u = ord[s];
      A  += sg[u]*w2l[u]*w1s[u];
      Bv += sg[u]*w2l[u]*b1s[u];
      AB[((s+1)*NN + tid)*2 + 0] = A;
      AB[((s+1)*NN + tid)*2 + 1] = Bv;
    }
  }
}

// ---------------- main ------------------------------------------------------
__global__ void __launch_bounds__(640)
sinkhorn_main(const float* __restrict__ random_,    // [256*200]
              const float* __restrict__ ordered_t,  // [2560*200]
              const float* __restrict__ random_t,   // [2560*200]
              const float* __restrict__ gumbel,     // [2560*200*200]
              const float* __restrict__ ws,
              float* __restrict__ out) {
  extern __shared__ u32 sm[];
  u32* KtT = sm;
  u32* aap = sm + AAP_OFF;
  u32* bbp = sm + BBP_OFF;
  float* wred = (float*)(sm + WRED_OFF);

  const int tid  = threadIdx.x;
  const int m    = blockIdx.x;
  const int bidx = m & 255;

  const int w    = tid >> 6;          // 0..9
  const int lane = tid & 63;
  const int cg   = lane & 7;          // bits 0-2: chunk group
  const int rgl  = (lane >> 3) & 7;   // bits 3-5
  const int rg   = w * 8 + rgl;       // 0..79
  const bool nr3 = (rg < 40);         // wave-uniform
  const int nr   = nr3 ? 3 : 2;       // rows/cols owned: {80d+rg : d<nr}
  const int cbase = 25*cg + (cg & 1); // even; csz 26/24
  const int csz   = 26 - 2*(cg & 1);
  const int coff  = 16*cg + 4*(cg >> 1);  // {0,16,36,52,72,88,108,124}

  // ---- zero KtT + aap + bbp (contiguous 28280 u32) -------------------------
  {
    const uint4 z = make_uint4(0u,0u,0u,0u);
    for (int i = tid; i < 7070; i += 640)
      *(uint4*)(sm + i*4) = z;
  }

  // ---- per-thread pair slots: j = 40d + rg/2 -> chunk cgb, coff layout -----
  int s0, s1, s2;
  {
    const int jb = rg >> 1;
#pragma unroll
    for (int d = 0; d < 3; ++d) {
      const int j = 40*d + jb;
      const int cgb = (j>=13)+(j>=25)+(j>=38)+(j>=50)+(j>=63)+(j>=75)+(j>=88);
      const int pairbase = (25*cgb + (cgb & 1)) >> 1;
      const int sl = 16*cgb + 4*(cgb >> 1) + j - pairbase;
      if (d == 0) s0 = sl; else if (d == 1) s1 = sl; else s2 = sl;
    }
  }

  // ---- build Kt[3][13] from gumbel (register staging) + MLP affine --------
  float xr[3] = {0.f, 0.f, 0.f}; int ii[3] = {0, 0, 0};
#pragma unroll
  for (int d = 0; d < 3; ++d)
    if (d < nr) xr[d] = random_[bidx*NN + 80*d + rg];
  for (int u = 0; u < 32; ++u) {
    const float kn = ws[u];
#pragma unroll
    for (int d = 0; d < 3; ++d) ii[d] += (kn < xr[d]) ? 1 : 0;
  }
  const float* ABt = ws + 32;
  const float* gmat = gumbel + (size_t)m * (NN*NN);

  u32 Kt[3][13];
#pragma unroll
  for (int d = 0; d < 3; ++d) {
    if (d < nr) {
      const float* grow = gmat + (size_t)(80*d + rg)*NN + cbase;
      float2 g[13];
#pragma unroll
      for (int k = 0; k < 13; ++k)
        g[k] = (2*k < csz) ? *(const float2*)(grow + 2*k) : make_float2(0.f, 0.f);
      const float x = xr[d];
      const float* ab = ABt + (size_t)(ii[d]*NN + cbase) * 2;
#pragma unroll
      for (int k = 0; k < 13; ++k) {
        u32 pk = 0;
        if (2*k < csz) {
          const float4 A = *(const float4*)(ab + 4*k);   // {A0,B0,A1,B1}
          pk = bpack(__expf(fmaf(x, A.x, A.y) + g[k].x),
                     __expf(fmaf(x, A.z, A.w) + g[k].y));
        }
        Kt[d][k] = pk;
      }
    } else {
#pragma unroll
      for (int k = 0; k < 13; ++k) Kt[d][k] = 0;
    }
  }
  __syncthreads();   // zero-fill complete before transpose writes

  // ---- transpose into KtT + init b = 1.0 packs ----------------------------
#pragma unroll
  for (int d = 0; d < 3; ++d) {
    if (d < nr) {
      const int sd = (d == 0) ? s0 : (d == 1) ? s1 : s2;
      u16* tb = (u16*)KtT;
      const int h = (rg & 1);
#pragma unroll
      for (int k = 0; k < 13; ++k) {
        if (2*k < csz) {
          tb[((cbase + 2*k    )*CSTR + sd)*2 + h] = (u16)(Kt[d][k] & 0xffffu);
          tb[((cbase + 2*k + 1)*CSTR + sd)*2 + h] = (u16)(Kt[d][k] >> 16);
        }
      }
    }
  }
  if (cg == 0 && !(rg & 1)) {
    bbp[s0] = 0x3f803f80u;
    bbp[s1] = 0x3f803f80u;
    if (nr3) bbp[s2] = 0x3f803f80u;
  }
  __syncthreads();

  // ---- 20 symmetric Sinkhorn iterations ------------------------------------
  const u32* bbv = bbp + coff;
  const u32* aav = aap + coff;
  float a0, a1, a2 = 0.f, b0 = 1.f, b1 = 1.f, b2 = 1.f;

  for (int it = 0; it < NITER; ++it) {
    // row pass: a_r = 1/sum_c K[r][c] b_c  (K from registers)
    u32 bv[13];
    *(uint4*)&bv[0] = *(const uint4*)(bbv);
    *(uint4*)&bv[4] = *(const uint4*)(bbv + 4);
    *(uint4*)&bv[8] = *(const uint4*)(bbv + 8);
    bv[12] = bbv[12];
    float c0 = 0.f, c1 = 0.f, c2 = 0.f;
#pragma unroll
    for (int k = 0; k < 13; ++k) {
      c0 = dot2bf(Kt[0][k], bv[k], c0);
      c1 = dot2bf(Kt[1][k], bv[k], c1);
      c2 = dot2bf(Kt[2][k], bv[k], c2);
    }
    c0 = swz_add<0x101F>(dpp_add<0x4E>(dpp_add<0xB1>(c0)));
    c1 = swz_add<0x101F>(dpp_add<0x4E>(dpp_add<0xB1>(c1)));
    c2 = swz_add<0x101F>(dpp_add<0x4E>(dpp_add<0xB1>(c2)));
    a0 = __builtin_amdgcn_rcpf(c0);
    a1 = __builtin_amdgcn_rcpf(c1);
    a2 = nr3 ? __builtin_amdgcn_rcpf(c2) : 0.f;
    {
      const float a0s = xch8(a0), a1s = xch8(a1), a2s = xch8(a2);
      if (cg == 0 && !(rg & 1)) {
        aap[s0] = bpack(a0, a0s);
        aap[s1] = bpack(a1, a1s);
        if (nr3) aap[s2] = bpack(a2, a2s);
      }
    }
    __syncthreads();

    // col pass: b_c = 1/sum_r K[r][c] a_r  (K^T from LDS, same shape)
    u32 av[13];
    *(uint4*)&av[0] = *(const uint4*)(aav);
    *(uint4*)&av[4] = *(const uint4*)(aav + 4);
    *(uint4*)&av[8] = *(const uint4*)(aav + 8);
    av[12] = aav[12];
    float e0 = 0.f, e1 = 0.f, e2 = 0.f;
#pragma unroll
    for (int d = 0; d < 3; ++d) {
      if (d < nr) {
        const u32* kc = KtT + (80*d + rg)*CSTR + coff;
        u32 kv[13];
        *(uint4*)&kv[0] = *(const uint4*)(kc);
        *(uint4*)&kv[4] = *(const uint4*)(kc + 4);
        *(uint4*)&kv[8] = *(const uint4*)(kc + 8);
        kv[12] = kc[12];
        float acc = 0.f;
#pragma unroll
        for (int k = 0; k < 13; ++k) acc = dot2bf(kv[k], av[k], acc);
        if (d == 0) e0 = acc; else if (d == 1) e1 = acc; else e2 = acc;
      }
    }
    e0 = swz_add<0x101F>(dpp_add<0x4E>(dpp_add<0xB1>(e0)));
    e1 = swz_add<0x101F>(dpp_add<0x4E>(dpp_add<0xB1>(e1)));
    e2 = swz_add<0x101F>(dpp_add<0x4E>(dpp_add<0xB1>(e2)));
    b0 = __builtin_amdgcn_rcpf(e0);
    b1 = __builtin_amdgcn_rcpf(e1);
    b2 = nr3 ? __builtin_amdgcn_rcpf(e2) : 0.f;
    {
      const float b0s = xch8(b0), b1s = xch8(b1), b2s = xch8(b2);
      if (cg == 0 && !(rg & 1)) {
        bbp[s0] = bpack(b0, b0s);
        bbp[s1] = bpack(b1, b1s);
        if (nr3) bbp[s2] = bpack(b2, b2s);
      }
    }
    __syncthreads();
  }

  // ---- loss: rec_c = b_c * sum_r K[r][c] (a_r * r_r) ------------------------
  {
    const float r0 = a0 * random_t[m*NN + rg];
    const float r1 = a1 * random_t[m*NN + 80 + rg];
    const float r2 = nr3 ? a2 * random_t[m*NN + 160 + rg] : 0.f;
    const float r0s = xch8(r0), r1s = xch8(r1), r2s = xch8(r2);
    if (cg == 0 && !(rg & 1)) {
      aap[s0] = bpack(r0, r0s);
      aap[s1] = bpack(r1, r1s);
      if (nr3) aap[s2] = bpack(r2, r2s);
    }
  }
  __syncthreads();
  float lacc = 0.f;
  {
    u32 av[13];
    *(uint4*)&av[0] = *(const uint4*)(aav);
    *(uint4*)&av[4] = *(const uint4*)(aav + 4);
    *(uint4*)&av[8] = *(const uint4*)(aav + 8);
    av[12] = aav[12];
    float e0 = 0.f, e1 = 0.f, e2 = 0.f;
#pragma unroll
    for (int d = 0; d < 3; ++d) {
      if (d < nr) {
        const u32* kc = KtT + (80*d + rg)*CSTR + coff;
        u32 kv[13];
        *(uint4*)&kv[0] = *(const uint4*)(kc);
        *(uint4*)&kv[4] = *(const uint4*)(kc + 4);
        *(uint4*)&kv[8] = *(const uint4*)(kc + 8);
        kv[12] = kc[12];
        float acc = 0.f;
#pragma unroll
        for (int k = 0; k < 13; ++k) acc = dot2bf(kv[k], av[k], acc);
        if (d == 0) e0 = acc; else if (d == 1) e1 = acc; else e2 = acc;
      }
    }
    e0 = swz_add<0x101F>(dpp_add<0x4E>(dpp_add<0xB1>(e0)));
    e1 = swz_add<0x101F>(dpp_add<0x4E>(dpp_add<0xB1>(e1)));
    e2 = swz_add<0x101F>(dpp_add<0x4E>(dpp_add<0xB1>(e2)));
    const float o0 = ordered_t[m*NN + rg];
    const float o1 = ordered_t[m*NN + 80 + rg];
    const float d0 = o0 - b0*e0;
    const float d1 = o1 - b1*e1;
    lacc = fmaf(d0, d0, d1*d1);
    if (nr3) {
      const float o2 = ordered_t[m*NN + 160 + rg];
      const float d2 = o2 - b2*e2;
      lacc = fmaf(d2, d2, lacc);
    }
    lacc = (cg == 0) ? lacc : 0.f;    // one count per column
  }
  lacc = dpp_add<0xB1>(lacc);
  lacc = dpp_add<0x4E>(lacc);
  lacc = swz_add<0x101F>(lacc);
  lacc = dpp_add<0x128>(lacc);
  lacc = pl16_add(lacc);
  lacc = pl32_add(lacc);
  if (lane == 0) wred[w] = lacc;
  __syncthreads();
  if (tid == 0) {
    float ssum = 0.f;
#pragma unroll
    for (int i = 0; i < 10; ++i) ssum += wred[i];
    atomicAdd(out, ssum * (1.0f / 512000.0f));
  }
}

extern "C" void kernel_launch(void* const* d_in, const int* in_sizes, int n_in,
                              void* d_out, int out_size, void* d_ws, size_t ws_size,
                              hipStream_t stream) {
  (void)in_sizes; (void)n_in; (void)ws_size; (void)out_size;
  const float* random_  = (const float*)d_in[0];
  const float* ordered  = (const float*)d_in[1];
  const float* random_t = (const float*)d_in[2];
  const float* gumbel   = (const float*)d_in[3];
  const float* W1 = (const float*)d_in[4];
  const float* b1 = (const float*)d_in[5];
  const float* W2 = (const float*)d_in[6];
  const float* b2 = (const float*)d_in[7];
  float* out = (float*)d_out;
  float* ws  = (float*)d_ws;   // needs 52,928 B

  const size_t smem = SM_U32 * sizeof(u32);  // 113,184 B
  hipFuncSetAttribute((const void*)sinkhorn_main,
                      hipFuncAttributeMaxDynamicSharedMemorySize, (int)smem);
  prep_kernel<<<1, 256, 0, stream>>>(W1, b1, W2, b2, ws);
  hipMemsetAsync(out, 0, sizeof(float), stream);
  sinkhorn_main<<<NMAT, 640, smem, stream>>>(random_, ordered, random_t, gumbel, ws, out);
}

// Round 13
// 373.110 us; speedup vs baseline: 1.3691x; 1.3660x over previous
//
#include <hip/hip_runtime.h>
#include <stdint.h>

// Round 13: 1024-thread WG (16 waves = 4/SIMD) in the 64-VGPR tier.
// r10 anchor (494us): lockstep phases serialize DS and VALU; 2.5 waves/SIMD
// can't hide LDS-load -> 13-dot-chain -> reduce-tree latency. 1-WG/CU is
// invariant (r9), so more waves must come from the WG itself.
// Row split 128 ways: thread owns rows {rg, 128+rg(if rg<72)} -> Kt[2][13]
// = 26 VGPR; steady state ~60 regs fits the 1024-thread allocator tier.
// Lane roles swapped: rgl = bits 0-2, cg = bits 3-5 -> BOTH reduce trees are
// xor8(dpp ror:8)/xor16(permlane16)/xor32(permlane32), all VALU (ds_swizzle
// leaves the per-iter DS path). Dot chains split into 2 accumulators.
// LDS constants = r10's exactly (CSTR 132, coff 16*cg, padded pair arrays).

#define NN 200
#define NMAT 2560
#define NITER 20
#define CSTR 132

// LDS layout (u32)
#define KTT_U32 26400    // 200 cols x 132
#define AAP_OFF 26400    // 128 (8 chunks x 16 pair slots)
#define BBP_OFF 26528    // 128
#define WRED_OFF 26656   // 16
#define SM_U32 26672     // 106,688 bytes

typedef uint32_t u32;
typedef uint16_t u16;

__device__ __forceinline__ u32 bpack(float lo, float hi){
  u32 a=__float_as_uint(lo); a += 0x7fffu + ((a>>16)&1u);
  u32 b=__float_as_uint(hi); b += 0x7fffu + ((b>>16)&1u);
  return (a>>16) | (b & 0xffff0000u);
}
__device__ __forceinline__ float dot2bf(u32 kp, u32 bp, float acc){
  asm("v_dot2_f32_bf16 %0, %1, %2, %0" : "+v"(acc) : "v"(kp), "v"(bp));
  return acc;
}
template<int CTRL>
__device__ __forceinline__ float dpp_add(float x){
  return x + __int_as_float(__builtin_amdgcn_update_dpp(0, __float_as_int(x), CTRL, 0xF, 0xF, true));
}
template<int PAT>
__device__ __forceinline__ float swz_add(float x){
  return x + __int_as_float(__builtin_amdgcn_ds_swizzle(__float_as_int(x), PAT));
}
__device__ __forceinline__ float xch1(float x){   // value from lane^1 (quad_perm 1,0,3,2)
  return __int_as_float(__builtin_amdgcn_update_dpp(0, __float_as_int(x), 0xB1, 0xF, 0xF, true));
}
__device__ __forceinline__ float pl16_add(float x){
#if __has_builtin(__builtin_amdgcn_permlane16_swap)
  auto r = __builtin_amdgcn_permlane16_swap(__float_as_uint(x), __float_as_uint(x), false, false);
  return __uint_as_float(r[0]) + __uint_as_float(r[1]);
#else
  return x + __shfl_xor(x, 16, 64);
#endif
}
__device__ __forceinline__ float pl32_add(float x){
#if __has_builtin(__builtin_amdgcn_permlane32_swap)
  auto r = __builtin_amdgcn_permlane32_swap(__float_as_uint(x), __float_as_uint(x), false, false);
  return __uint_as_float(r[0]) + __uint_as_float(r[1]);
#else
  return x + __shfl_xor(x, 32, 64);
#endif
}
// reduce over cg (lane bits 3-5): xor8 + xor16 + xor32, all VALU
__device__ __forceinline__ float cg_reduce(float x){
  x = dpp_add<0x128>(x);   // xor8 (row_ror:8)
  x = pl16_add(x);         // xor16
  x = pl32_add(x);         // xor32
  return x;
}

// ---------------- prep: piecewise-affine MLP coefficients ------------------
// ws (f32): [0..32) knots (unsorted); [32..) AB[33][200][2] interleaved.
__global__ void __launch_bounds__(256)
prep_kernel(const float* __restrict__ W1, const float* __restrict__ b1,
            const float* __restrict__ W2, const float* __restrict__ b2,
            float* __restrict__ ws) {
  __shared__ float kn[32], sg[32], w1s[32], b1s[32];
  __shared__ int ord[32];
  const int tid = threadIdx.x;
  if (tid < 32) {
    const float w1 = W1[tid], bv = b1[tid];
    float knot, s;
    if (w1 != 0.f) { knot = -bv / w1; s = (w1 > 0.f) ? 1.f : -1.f; }
    else           { knot = (bv > 0.f) ? -1e30f : 1e30f; s = 1.f; }
    kn[tid] = knot; sg[tid] = s; w1s[tid] = w1; b1s[tid] = bv;
    ws[tid] = knot;
  }
  __syncthreads();
  if (tid < 32) {
    int rk = 0;
#pragma unroll
    for (int v = 0; v < 32; ++v) {
      const float kv = kn[v];
      rk += (kv < kn[tid] || (kv == kn[tid] && v < tid)) ? 1 : 0;
    }
    ord[rk] = tid;
  }
  __syncthreads();
  if (tid < NN) {
    float w2l[32];
#pragma unroll
    for (int u = 0; u < 32; ++u) w2l[u] = W2[tid*32 + u];
    float A = 0.f, Bv = b2[tid];
#pragma unroll
    for (int u = 0; u < 32; ++u)
      if (sg[u] < 0.f) { A += w2l[u]*w1s[u]; Bv += w2l[u]*b1s[u]; }
    float* AB = ws + 32;
    AB[(0*NN + tid)*2 + 0] = A;
    AB[(0*NN + tid)*2 + 1] = Bv;
    for (int s = 0; s < 32; ++s) {
      const int u = ord[s];
      A  += sg[u]*w2l[u]*w1s[u];
      Bv += sg[u]*w2l[u]*b1s[u];
      AB[((s+1)*NN + tid)*2 + 0] = A;
      AB[((s+1)*NN + tid)*2 + 1] = Bv;
    }
  }
}

// ---------------- main ------------------------------------------------------
__global__ void __launch_bounds__(1024)
sinkhorn_main(const float* __restrict__ random_,    // [256*200]
              const float* __restrict__ ordered_t,  // [2560*200]
              const float* __restrict__ random_t,   // [2560*200]
              const float* __restrict__ gumbel,     // [2560*200*200]
              const float* __restrict__ ws,
              float* __restrict__ out) {
  extern __shared__ u32 sm[];
  u32* KtT = sm;
  u32* aap = sm + AAP_OFF;
  u32* bbp = sm + BBP_OFF;
  float* wred = (float*)(sm + WRED_OFF);

  const int tid  = threadIdx.x;
  const int m    = blockIdx.x;
  const int bidx = m & 255;

  const int w    = tid >> 6;          // 0..15
  const int lane = tid & 63;
  const int rgl  = lane & 7;          // bits 0-2: row-within-wave
  const int cg   = (lane >> 3) & 7;   // bits 3-5: col-chunk group
  const int rg   = w * 8 + rgl;       // 0..127; rows/cols {128d + rg : d < nr}
  const bool nr2 = (rg < 72);         // wave-uniform (w<9)
  const int cbase = 25*cg + (cg & 1);
  const int csz   = 26 - 2*(cg & 1);
  const int coff  = 16*cg;

  // ---- zero whole LDS block ------------------------------------------------
  {
    const uint4 z = make_uint4(0u,0u,0u,0u);
    for (int i = tid; i < SM_U32/4; i += 1024)
      *(uint4*)(sm + i*4) = z;
  }

  // ---- pair slots for j = 64d + rg/2 (pairs of adjacent rows/cols) ---------
  int s0, s1;
  {
    const int jb = rg >> 1;
#pragma unroll
    for (int d = 0; d < 2; ++d) {
      const int j = 64*d + jb;
      const int cgb = (j>=13)+(j>=25)+(j>=38)+(j>=50)+(j>=63)+(j>=75)+(j>=88);
      const int sl = 16*cgb + j - ((25*cgb + (cgb & 1)) >> 1);
      if (d == 0) s0 = sl; else s1 = sl;
    }
  }

  // ---- build Kt[2][13] (register-staged gumbel + affine MLP) ---------------
  float xr[2] = {0.f, 0.f}; int ii[2] = {0, 0};
  xr[0] = random_[bidx*NN + rg];
  if (nr2) xr[1] = random_[bidx*NN + 128 + rg];
  for (int u = 0; u < 32; ++u) {
    const float kn = ws[u];
    ii[0] += (kn < xr[0]) ? 1 : 0;
    ii[1] += (kn < xr[1]) ? 1 : 0;
  }
  const float* ABt = ws + 32;
  const float* gmat = gumbel + (size_t)m * (NN*NN);

  u32 Kt[2][13];
#pragma unroll
  for (int d = 0; d < 2; ++d) {
    if (d == 0 || nr2) {
      const float* grow = gmat + (size_t)(128*d + rg)*NN + cbase;
      float2 g[13];
#pragma unroll
      for (int k = 0; k < 13; ++k)
        g[k] = (2*k < csz) ? *(const float2*)(grow + 2*k) : make_float2(0.f, 0.f);
      const float x = xr[d];
      const float* ab = ABt + (size_t)(ii[d]*NN + cbase) * 2;
#pragma unroll
      for (int k = 0; k < 13; ++k) {
        u32 pk = 0;
        if (2*k < csz) {
          const float4 A = *(const float4*)(ab + 4*k);   // {A0,B0,A1,B1}
          pk = bpack(__expf(fmaf(x, A.x, A.y) + g[k].x),
                     __expf(fmaf(x, A.z, A.w) + g[k].y));
        }
        Kt[d][k] = pk;
      }
    }
  }
  __syncthreads();   // zero-fill visible before transpose/init writes

  // ---- transpose into KtT + init b = 1.0 pairs -----------------------------
#pragma unroll
  for (int d = 0; d < 2; ++d) {
    if (d == 0 || nr2) {
      const int sd = (d == 0) ? s0 : s1;
      u16* tb = (u16*)KtT;
      const int h = (rg & 1);
#pragma unroll
      for (int k = 0; k < 13; ++k) {
        if (2*k < csz) {
          tb[((cbase + 2*k    )*CSTR + sd)*2 + h] = (u16)(Kt[d][k] & 0xffffu);
          tb[((cbase + 2*k + 1)*CSTR + sd)*2 + h] = (u16)(Kt[d][k] >> 16);
        }
      }
    }
  }
  if (cg == 0 && !(rg & 1)) {
    bbp[s0] = 0x3f803f80u;
    if (nr2) bbp[s1] = 0x3f803f80u;
  }
  __syncthreads();

  // ---- 20 symmetric Sinkhorn iterations ------------------------------------
  const u32* bbv = bbp + coff;
  const u32* aav = aap + coff;
  float a0, a1 = 0.f, b0 = 1.f, b1 = 1.f;

  for (int it = 0; it < NITER; ++it) {
    // row pass: a_r = 1/sum_c K[r][c] b_c  (K from registers)
    u32 bv[13];
    *(uint4*)&bv[0] = *(const uint4*)(bbv);
    *(uint4*)&bv[4] = *(const uint4*)(bbv + 4);
    *(uint4*)&bv[8] = *(const uint4*)(bbv + 8);
    bv[12] = bbv[12];
    {
      float cA = 0.f, cB = 0.f;
#pragma unroll
      for (int k = 0; k < 6; ++k) cA = dot2bf(Kt[0][k], bv[k], cA);
#pragma unroll
      for (int k = 6; k < 13; ++k) cB = dot2bf(Kt[0][k], bv[k], cB);
      a0 = __builtin_amdgcn_rcpf(cg_reduce(cA + cB));
    }
    if (nr2) {
      float cA = 0.f, cB = 0.f;
#pragma unroll
      for (int k = 0; k < 6; ++k) cA = dot2bf(Kt[1][k], bv[k], cA);
#pragma unroll
      for (int k = 6; k < 13; ++k) cB = dot2bf(Kt[1][k], bv[k], cB);
      a1 = __builtin_amdgcn_rcpf(cg_reduce(cA + cB));
    }
    if (cg == 0 && !(rg & 1)) {
      aap[s0] = bpack(a0, xch1(a0));
      if (nr2) aap[s1] = bpack(a1, xch1(a1));
    }
    __syncthreads();

    // col pass: b_c = 1/sum_r K[r][c] a_r  (K^T from LDS, same shape)
    u32 av[13];
    *(uint4*)&av[0] = *(const uint4*)(aav);
    *(uint4*)&av[4] = *(const uint4*)(aav + 4);
    *(uint4*)&av[8] = *(const uint4*)(aav + 8);
    av[12] = aav[12];
    {
      const u32* kc = KtT + (size_t)rg*CSTR + coff;
      u32 kv[13];
      *(uint4*)&kv[0] = *(const uint4*)(kc);
      *(uint4*)&kv[4] = *(const uint4*)(kc + 4);
      *(uint4*)&kv[8] = *(const uint4*)(kc + 8);
      kv[12] = kc[12];
      float eA = 0.f, eB = 0.f;
#pragma unroll
      for (int k = 0; k < 6; ++k) eA = dot2bf(kv[k], av[k], eA);
#pragma unroll
      for (int k = 6; k < 13; ++k) eB = dot2bf(kv[k], av[k], eB);
      b0 = __builtin_amdgcn_rcpf(cg_reduce(eA + eB));
    }
    if (nr2) {
      const u32* kc = KtT + (size_t)(128 + rg)*CSTR + coff;
      u32 kv[13];
      *(uint4*)&kv[0] = *(const uint4*)(kc);
      *(uint4*)&kv[4] = *(const uint4*)(kc + 4);
      *(uint4*)&kv[8] = *(const uint4*)(kc + 8);
      kv[12] = kc[12];
      float eA = 0.f, eB = 0.f;
#pragma unroll
      for (int k = 0; k < 6; ++k) eA = dot2bf(kv[k], av[k], eA);
#pragma unroll
      for (int k = 6; k < 13; ++k) eB = dot2bf(kv[k], av[k], eB);
      b1 = __builtin_amdgcn_rcpf(cg_reduce(eA + eB));
    }
    if (cg == 0 && !(rg & 1)) {
      bbp[s0] = bpack(b0, xch1(b0));
      if (nr2) bbp[s1] = bpack(b1, xch1(b1));
    }
    __syncthreads();
  }

  // ---- loss: rec_c = b_c * sum_r K[r][c] (a_r * r_r) ------------------------
  {
    const float r0 = a0 * random_t[m*NN + rg];
    const float r1 = nr2 ? a1 * random_t[m*NN + 128 + rg] : 0.f;
    if (cg == 0 && !(rg & 1)) {
      aap[s0] = bpack(r0, xch1(r0));
      if (nr2) aap[s1] = bpack(r1, xch1(r1));
    }
  }
  __syncthreads();
  float lacc = 0.f;
  {
    u32 av[13];
    *(uint4*)&av[0] = *(const uint4*)(aav);
    *(uint4*)&av[4] = *(const uint4*)(aav + 4);
    *(uint4*)&av[8] = *(const uint4*)(aav + 8);
    av[12] = aav[12];
    float e0;
    {
      const u32* kc = KtT + (size_t)rg*CSTR + coff;
      u32 kv[13];
      *(uint4*)&kv[0] = *(const uint4*)(kc);
      *(uint4*)&kv[4] = *(const uint4*)(kc + 4);
      *(uint4*)&kv[8] = *(const uint4*)(kc + 8);
      kv[12] = kc[12];
      float eA = 0.f, eB = 0.f;
#pragma unroll
      for (int k = 0; k < 6; ++k) eA = dot2bf(kv[k], av[k], eA);
#pragma unroll
      for (int k = 6; k < 13; ++k) eB = dot2bf(kv[k], av[k], eB);
      e0 = cg_reduce(eA + eB);
    }
    const float o0 = ordered_t[m*NN + rg];
    const float d0 = o0 - b0*e0;
    lacc = d0*d0;
    if (nr2) {
      const u32* kc = KtT + (size_t)(128 + rg)*CSTR + coff;
      u32 kv[13];
      *(uint4*)&kv[0] = *(const uint4*)(kc);
      *(uint4*)&kv[4] = *(const uint4*)(kc + 4);
      *(uint4*)&kv[8] = *(const uint4*)(kc + 8);
      kv[12] = kc[12];
      float eA = 0.f, eB = 0.f;
#pragma unroll
      for (int k = 0; k < 6; ++k) eA = dot2bf(kv[k], av[k], eA);
#pragma unroll
      for (int k = 6; k < 13; ++k) eB = dot2bf(kv[k], av[k], eB);
      const float e1 = cg_reduce(eA + eB);
      const float o1 = ordered_t[m*NN + 128 + rg];
      const float d1 = o1 - b1*e1;
      lacc = fmaf(d1, d1, lacc);
    }
    lacc = (cg == 0) ? lacc : 0.f;    // one count per column
  }
  // full 64-lane sum
  lacc = dpp_add<0xB1>(lacc);
  lacc = dpp_add<0x4E>(lacc);
  lacc = swz_add<0x101F>(lacc);
  lacc = dpp_add<0x128>(lacc);
  lacc = pl16_add(lacc);
  lacc = pl32_add(lacc);
  if (lane == 0) wred[w] = lacc;
  __syncthreads();
  if (tid == 0) {
    float ssum = 0.f;
#pragma unroll
    for (int i = 0; i < 16; ++i) ssum += wred[i];
    atomicAdd(out, ssum * (1.0f / 512000.0f));
  }
}

extern "C" void kernel_launch(void* const* d_in, const int* in_sizes, int n_in,
                              void* d_out, int out_size, void* d_ws, size_t ws_size,
                              hipStream_t stream) {
  (void)in_sizes; (void)n_in; (void)ws_size; (void)out_size;
  const float* random_  = (const float*)d_in[0];
  const float* ordered  = (const float*)d_in[1];
  const float* random_t = (const float*)d_in[2];
  const float* gumbel   = (const float*)d_in[3];
  const float* W1 = (const float*)d_in[4];
  const float* b1 = (const float*)d_in[5];
  const float* W2 = (const float*)d_in[6];
  const float* b2 = (const float*)d_in[7];
  float* out = (float*)d_out;
  float* ws  = (float*)d_ws;   // needs 52,928 B

  const size_t smem = SM_U32 * sizeof(u32);  // 106,688 B
  hipFuncSetAttribute((const void*)sinkhorn_main,
                      hipFuncAttributeMaxDynamicSharedMemorySize, (int)smem);
  prep_kernel<<<1, 256, 0, stream>>>(W1, b1, W2, b2, ws);
  hipMemsetAsync(out, 0, sizeof(float), stream);
  sinkhorn_main<<<NMAT, 1024, smem, stream>>>(random_, ordered, random_t, gumbel, ws, out);
}